// Round 7
// baseline (148.027 us; speedup 1.0000x reference)
//
#include <hip/hip_runtime.h>
#include <hip/hip_bf16.h>

// y[b,i,j,u] = relu( sum_{c,h} w[u,c,i,h] * x[b,h,j,c] )
// B=16,H=64,W=64,C=64,U=128
// GEMM: M=(b,j)=1024, N=(i,u)=8192 (n=i*128+u), K=(h,c)=4096, kappa=h*64+c.
//
// Pass 1a: Xb[b][h][j][c] = bf16(x)                      (8.39 MB, ws+0)
// Pass 1b: Wb[i][u][h][c] = bf16(w[u][c][i][h])          (64 MB,  ws+8388608)
// Pass 2 : BM=256 x BN=128 x BK=64, 4 FAT waves (2x2, 128x64 each) --
//          fragment LDS traffic 98KB/step (vs 128KB at 8x 64x64) so the LDS
//          pipe floor (~1300cy) matches the MFMA floor (1242cy). Triple-
//          buffered LDS, read-ahead fragment pipelining, counted vmcnt(8)
//          (T4), 2 barriers/K-step, XOR swizzle (T2), XCD chunking so the 4
//          blocks sharing a B-panel share an XCD L2 (T1). Grid=256 = 1/CU.

typedef __attribute__((ext_vector_type(4))) float f32x4;
typedef __attribute__((ext_vector_type(8))) short bf16x8;
typedef __attribute__((ext_vector_type(4))) unsigned int u32x4;
typedef __attribute__((ext_vector_type(2))) unsigned int u32x2;
typedef unsigned short ushort_t;

static __device__ __forceinline__ unsigned int cvt_pk_bf16(float lo, float hi) {
  unsigned int r;
  asm("v_cvt_pk_bf16_f32 %0, %1, %2" : "=v"(r) : "v"(lo), "v"(hi));
  return r;
}

static __device__ __forceinline__ void async_copy16(void* lds, const void* g) {
  __builtin_amdgcn_global_load_lds(
      (const __attribute__((address_space(1))) unsigned int*)g,
      (__attribute__((address_space(3))) unsigned int*)lds, 16, 0, 0);
}

// ---------------- Pass 1a: x f32 -> bf16 (straight) ----------------
__global__ __launch_bounds__(256)
void conv_x(const float* __restrict__ X, ushort_t* __restrict__ Xb, int n4) {
  int idx = blockIdx.x * 256 + threadIdx.x;
  const int stride = gridDim.x * 256;
  for (; idx < n4; idx += stride) {
    f32x4 v = ((const f32x4*)X)[idx];
    u32x2 o;
    o.x = cvt_pk_bf16(v.x, v.y);
    o.y = cvt_pk_bf16(v.z, v.w);
    ((u32x2*)Xb)[idx] = o;
  }
}

// ---------------- Pass 1b: w[u][c][i][h] -> Wb[i][u][h][c] bf16 ----------------
__global__ __launch_bounds__(256)
void conv_w(const float* __restrict__ W, ushort_t* __restrict__ Wb) {
  __shared__ float T[64][65];  // [c][h], +1 pad
  const int bid = blockIdx.x;       // 8192 blocks = u*64 + i
  const int u = bid >> 6;
  const int i = bid & 63;
  const int t = threadIdx.x;

  const int hq = t & 15;            // 16B chunk of h-row
  const int c4 = t >> 4;            // 0..15
  const float* base = W + (((size_t)u * 64) * 64 + i) * 64;  // + c*4096 + h
#pragma unroll
  for (int it = 0; it < 4; ++it) {
    const int c = it * 16 + c4;
    f32x4 v = *(const f32x4*)(base + (size_t)c * 4096 + hq * 4);
    *(f32x4*)&T[c][hq * 4] = v;
  }
  __syncthreads();

  const int h = t >> 2;
  const int c0 = (t & 3) * 16;
  unsigned int pk[8];
#pragma unroll
  for (int q = 0; q < 8; ++q)
    pk[q] = cvt_pk_bf16(T[c0 + 2 * q][h], T[c0 + 2 * q + 1][h]);
  ushort_t* out = Wb + (((size_t)i * 128 + u) * 64 + h) * 64 + c0;
  ((u32x4*)out)[0] = *(u32x4*)&pk[0];
  ((u32x4*)out)[1] = *(u32x4*)&pk[4];
}

// ---------------- Pass 2: bf16 GEMM, 4 fat waves, read-ahead schedule --------
__global__ __launch_bounds__(256, 1)
void gemm4f(const ushort_t* __restrict__ Xb, const ushort_t* __restrict__ Wb,
            float* __restrict__ O) {
  __shared__ ushort_t As[3][256 * 64];  // 32KB each, XOR-swizzled rows
  __shared__ ushort_t Bs[3][128 * 64];  // 16KB each

  const int tid = threadIdx.x;
  const int lane = tid & 63;
  const int wid = tid >> 6;         // 4 waves
  const int wm = wid >> 1;          // 0..1 : 128-row m slab
  const int wn = wid & 1;           // 0..1 : 64-col n slab

  const int bid = blockIdx.x;       // 256 blocks; XCD-bijective chunking
  const int wg = (bid & 7) * 32 + (bid >> 3);
  const int mt = wg & 3;            // 4 m-tiles of 256 (adjacent wg share nt)
  const int nt = wg >> 2;           // 64 n-tiles of 128 == output i

  const char* XbB = (const char*)Xb;
  const char* WbB = (const char*)Wb;

  // ---- staging geometry: LDS dest lane-linear, source carries the XOR ----
  // A tile: 256 rows x 64 kappa (32KB) -> 8 x 16B chunks per thread
  int a_dst[8]; size_t a_src[8];
#pragma unroll
  for (int it = 0; it < 8; ++it) {
    const int flat = it * 4096 + tid * 16;
    const int row = flat >> 7;            // m_local 0..255
    const int p = (flat >> 4) & 7;        // physical 16B slot
    const int b = mt * 4 + (row >> 6);
    const int j = row & 63;
    a_dst[it] = flat;
    a_src[it] = (size_t)b * 524288 + (size_t)j * 128 + ((p ^ (row & 7)) << 4);
  }
  // B tile: 128 rows (u) x 64 kappa (16KB) -> 4 x 16B chunks per thread
  int b_dst[4]; size_t b_src[4];
#pragma unroll
  for (int it = 0; it < 4; ++it) {
    const int flat = it * 4096 + tid * 16;
    const int u = flat >> 7;              // n_local 0..127
    const int p = (flat >> 4) & 7;
    b_dst[it] = flat;
    b_src[it] = (size_t)(nt * 128 + u) * 8192 + ((p ^ (u & 7)) << 4);
  }

  // ---- fragment ds_read offsets (buffer-relative, per kk) ----
  int a_ro[2][8], b_ro[2][4];
#pragma unroll
  for (int kk = 0; kk < 2; ++kk) {
#pragma unroll
    for (int f = 0; f < 8; ++f) {
      const int row = wm * 128 + f * 16 + (lane & 15);
      const int byte0 = row * 128 + kk * 64 + (lane >> 4) * 16;
      a_ro[kk][f] = byte0 ^ ((row & 7) << 4);
    }
#pragma unroll
    for (int f = 0; f < 4; ++f) {
      const int row = wn * 64 + f * 16 + (lane & 15);
      const int byte0 = row * 128 + kk * 64 + (lane >> 4) * 16;
      b_ro[kk][f] = byte0 ^ ((row & 7) << 4);
    }
  }

  f32x4 acc[8][4];
#pragma unroll
  for (int i = 0; i < 8; ++i)
#pragma unroll
    for (int j = 0; j < 4; ++j) acc[i][j] = (f32x4){0.f, 0.f, 0.f, 0.f};

  auto stageA = [&](int buf, int h) {   // 8 async loads
    char* la = (char*)&As[buf][0];
#pragma unroll
    for (int it = 0; it < 8; ++it)
      async_copy16(la + a_dst[it], XbB + a_src[it] + (size_t)h * 8192);
  };
  auto stageB = [&](int buf, int h) {   // 4 async loads
    char* lb = (char*)&Bs[buf][0];
#pragma unroll
    for (int it = 0; it < 4; ++it)
      async_copy16(lb + b_dst[it], WbB + b_src[it] + (size_t)h * 128);
  };

  // fragment register sets: set0 holds kk=0 frags, set1 holds kk=1 frags
  bf16x8 fa0[8], fb0[4], fa1[8], fb1[4];

  auto readFrags = [&](bf16x8 (&fa)[8], bf16x8 (&fb)[4], int buf, int kk) {
    const char* ab = (const char*)&As[buf][0];
    const char* bb = (const char*)&Bs[buf][0];
#pragma unroll
    for (int f = 0; f < 8; ++f) fa[f] = *(const bf16x8*)(ab + a_ro[kk][f]);
#pragma unroll
    for (int f = 0; f < 4; ++f) fb[f] = *(const bf16x8*)(bb + b_ro[kk][f]);
  };

  // ---- prologue: stage tiles 0,1 (12 loads each); drain tile 0 ----
  stageA(0, 0); stageB(0, 0);
  stageA(1, 1); stageB(1, 1);
  asm volatile("s_waitcnt vmcnt(12)" ::: "memory");
  __builtin_amdgcn_s_barrier();
  readFrags(fa0, fb0, 0, 0);

  int cur = 0, nxt = 1, pre = 2;
  for (int t = 0; t < 64; ++t) {
    // ===== phase 0: preload kk=1 of tile t, issue A(t+2), certify t+1 =====
    __builtin_amdgcn_sched_barrier(0);
    readFrags(fa1, fb1, cur, 1);
    if (t + 2 < 64) stageA(pre, t + 2);
    // drain tile t+1's 12 staging loads; keep the 8 A-loads just issued
    if (t < 62) {
      asm volatile("s_waitcnt vmcnt(8)" ::: "memory");
    } else {
      asm volatile("s_waitcnt vmcnt(0)" ::: "memory");
    }
    __builtin_amdgcn_sched_barrier(0);
    __builtin_amdgcn_s_barrier();
    __builtin_amdgcn_s_setprio(1);
#pragma unroll
    for (int mf = 0; mf < 8; ++mf)
#pragma unroll
      for (int nf = 0; nf < 4; ++nf)
        acc[mf][nf] = __builtin_amdgcn_mfma_f32_16x16x32_bf16(
            fa0[mf], fb0[nf], acc[mf][nf], 0, 0, 0);
    __builtin_amdgcn_s_setprio(0);

    // ===== phase 1: preload kk=0 of tile t+1, issue B(t+2), compute kk=1 =====
    __builtin_amdgcn_sched_barrier(0);
    if (t + 1 < 64) readFrags(fa0, fb0, nxt, 0);
    if (t + 2 < 64) stageB(pre, t + 2);
    __builtin_amdgcn_s_setprio(1);
#pragma unroll
    for (int mf = 0; mf < 8; ++mf)
#pragma unroll
      for (int nf = 0; nf < 4; ++nf)
        acc[mf][nf] = __builtin_amdgcn_mfma_f32_16x16x32_bf16(
            fa1[mf], fb1[nf], acc[mf][nf], 0, 0, 0);
    __builtin_amdgcn_s_setprio(0);
    // end-of-step barrier: all waves' reads of buf[cur] are consumed (their
    // kk=1 MFMAs above lgkm-waited), so buf[cur] may be overwritten at t+1.
    __builtin_amdgcn_s_barrier();

    cur = (cur == 2) ? 0 : cur + 1;
    nxt = (nxt == 2) ? 0 : nxt + 1;
    pre = (pre == 2) ? 0 : pre + 1;
  }

  // ---- epilogue: relu + scatter to y[b, i=nt, j, u] ----
  const int rbase = (lane >> 4) * 4;
  const int cn = lane & 15;
#pragma unroll
  for (int mf = 0; mf < 8; ++mf) {
#pragma unroll
    for (int r = 0; r < 4; ++r) {
      const int ml = wm * 128 + mf * 16 + rbase + r;
      const int m = mt * 256 + ml;
      const int b = m >> 6;
      const int j = m & 63;
      float* orow = O + (((size_t)b * 64 + nt) * 64 + j) * 128;
#pragma unroll
      for (int nf = 0; nf < 4; ++nf) {
        const int u = wn * 64 + nf * 16 + cn;
        orow[u] = fmaxf(acc[mf][nf][r], 0.f);
      }
    }
  }
}

// ---------------- Fallback (round-1 fused kernel, used only if ws too small) ----
__global__ __launch_bounds__(256, 2)
void fused_gemm(const float* __restrict__ X, const float* __restrict__ Wt,
                float* __restrict__ O) {
  __shared__ ushort_t As[2][128 * 64];
  __shared__ ushort_t Bs[2][128 * 64];
  const int tid = threadIdx.x;
  const int lane = tid & 63;
  const int wid = tid >> 6;
  const int wm = wid >> 1;
  const int wn = wid & 1;
  const int bid = blockIdx.x;
  const int wg = (bid & 7) * 64 + (bid >> 3);
  const int mt = wg & 7;
  const int nt = wg >> 3;
  const int a_ml = tid >> 1;
  const int a_hp = (tid & 1) * 2;
  const int a_b = (mt * 128 + a_ml) >> 6;
  const int a_j = a_ml & 63;
  const float* a_base = X + ((size_t)a_b << 18) + ((size_t)a_j << 6);
  const int b_nl = tid >> 1;
  const int b_c8 = (tid & 1) * 8;
  const float* b_base = Wt + ((size_t)b_nl << 18) + ((size_t)nt << 6);
  f32x4 ra[2][4];
  f32x4 rb[8];
  f32x4 acc[4][4];
#pragma unroll
  for (int i = 0; i < 4; ++i)
#pragma unroll
    for (int j = 0; j < 4; ++j) acc[i][j] = (f32x4){0.f, 0.f, 0.f, 0.f};
  auto stage_load = [&](int t) {
    const int th = t & 15;
    const int tc = t >> 4;
    const int c0 = tc * 16;
    const int h0 = th * 4;
#pragma unroll
    for (int s = 0; s < 2; ++s) {
      const float* p = a_base + (size_t)(h0 + a_hp + s) * 4096 + c0;
#pragma unroll
      for (int q = 0; q < 4; ++q) ra[s][q] = ((const f32x4*)p)[q];
    }
#pragma unroll
    for (int q = 0; q < 8; ++q)
      rb[q] = *(const f32x4*)(b_base + (size_t)(c0 + b_c8 + q) * 4096 + h0);
  };
  auto stage_write = [&](int buf) {
    char* abase = (char*)&As[buf][0];
    const int swa = (a_ml & 7) << 4;
#pragma unroll
    for (int s = 0; s < 2; ++s) {
      u32x4 lo, hi;
      lo.x = cvt_pk_bf16(ra[s][0].x, ra[s][0].y);
      lo.y = cvt_pk_bf16(ra[s][0].z, ra[s][0].w);
      lo.z = cvt_pk_bf16(ra[s][1].x, ra[s][1].y);
      lo.w = cvt_pk_bf16(ra[s][1].z, ra[s][1].w);
      hi.x = cvt_pk_bf16(ra[s][2].x, ra[s][2].y);
      hi.y = cvt_pk_bf16(ra[s][2].z, ra[s][2].w);
      hi.z = cvt_pk_bf16(ra[s][3].x, ra[s][3].y);
      hi.w = cvt_pk_bf16(ra[s][3].z, ra[s][3].w);
      const int byte0 = a_ml * 128 + (a_hp + s) * 32;
      *(u32x4*)(abase + (byte0 ^ swa)) = lo;
      *(u32x4*)(abase + ((byte0 + 16) ^ swa)) = hi;
    }
    char* bbase = (char*)&Bs[buf][0];
    const int swb = (b_nl & 7) << 4;
#pragma unroll
    for (int hl = 0; hl < 4; ++hl) {
      u32x4 v;
      v.x = cvt_pk_bf16(rb[0][hl], rb[1][hl]);
      v.y = cvt_pk_bf16(rb[2][hl], rb[3][hl]);
      v.z = cvt_pk_bf16(rb[4][hl], rb[5][hl]);
      v.w = cvt_pk_bf16(rb[6][hl], rb[7][hl]);
      const int byte0 = b_nl * 128 + (hl * 16 + b_c8) * 2;
      *(u32x4*)(bbase + (byte0 ^ swb)) = v;
    }
  };
  auto compute = [&](int buf) {
    const char* abase = (const char*)&As[buf][0];
    const char* bbase = (const char*)&Bs[buf][0];
#pragma unroll
    for (int kk = 0; kk < 2; ++kk) {
      bf16x8 af[4], bfr[4];
#pragma unroll
      for (int mf = 0; mf < 4; ++mf) {
        const int row = wm * 64 + mf * 16 + (lane & 15);
        const int byte0 = row * 128 + kk * 64 + (lane >> 4) * 16;
        af[mf] = *(const bf16x8*)(abase + (byte0 ^ ((row & 7) << 4)));
      }
#pragma unroll
      for (int nf = 0; nf < 4; ++nf) {
        const int row = wn * 64 + nf * 16 + (lane & 15);
        const int byte0 = row * 128 + kk * 64 + (lane >> 4) * 16;
        bfr[nf] = *(const bf16x8*)(bbase + (byte0 ^ ((row & 7) << 4)));
      }
#pragma unroll
      for (int mf = 0; mf < 4; ++mf)
#pragma unroll
        for (int nf = 0; nf < 4; ++nf)
          acc[mf][nf] = __builtin_amdgcn_mfma_f32_16x16x32_bf16(
              af[mf], bfr[nf], acc[mf][nf], 0, 0, 0);
    }
  };
  stage_load(0);
  stage_write(0);
  __syncthreads();
  int cur = 0;
  for (int t = 0; t < 64; ++t) {
    if (t + 1 < 64) stage_load(t + 1);
    compute(cur);
    if (t + 1 < 64) stage_write(cur ^ 1);
    __syncthreads();
    cur ^= 1;
  }
  const int rbase = (lane >> 4) * 4;
  const int cn = lane & 15;
#pragma unroll
  for (int mf = 0; mf < 4; ++mf) {
#pragma unroll
    for (int r = 0; r < 4; ++r) {
      const int ml = wm * 64 + mf * 16 + rbase + r;
      const int m = mt * 128 + ml;
      const int b = m >> 6;
      const int j = m & 63;
      float* orow = O + (((size_t)b * 64 + nt) * 64 + j) * 128;
#pragma unroll
      for (int nf = 0; nf < 4; ++nf) {
        const int u = wn * 64 + nf * 16 + cn;
        orow[u] = fmaxf(acc[mf][nf][r], 0.f);
      }
    }
  }
}

extern "C" void kernel_launch(void* const* d_in, const int* in_sizes, int n_in,
                              void* d_out, int out_size, void* d_ws, size_t ws_size,
                              hipStream_t stream) {
  const float* x = (const float*)d_in[0];   // (16,64,64,64) f32
  const float* w = (const float*)d_in[1];   // (128,64,64,64) f32
  float* out = (float*)d_out;               // (16,64,64,128) f32

  const size_t XB_BYTES = (size_t)16 * 64 * 64 * 64 * 2;    // 8,388,608
  const size_t WB_BYTES = (size_t)64 * 128 * 64 * 64 * 2;   // 67,108,864

  if (ws_size >= XB_BYTES + WB_BYTES) {
    ushort_t* Xb = (ushort_t*)d_ws;
    ushort_t* Wb = (ushort_t*)((char*)d_ws + XB_BYTES);
    hipLaunchKernelGGL(conv_x, dim3(1024), dim3(256), 0, stream, x, Xb,
                       (int)(16 * 64 * 64 * 64 / 4));
    hipLaunchKernelGGL(conv_w, dim3(8192), dim3(256), 0, stream, w, Wb);
    hipLaunchKernelGGL(gemm4f, dim3(256), dim3(256), 0, stream, Xb, Wb, out);
  } else {
    hipLaunchKernelGGL(fused_gemm, dim3(512), dim3(256), 0, stream, x, w, out);
  }
}

// Round 8
// 131.967 us; speedup vs baseline: 1.1217x; 1.1217x over previous
//
#include <hip/hip_runtime.h>
#include <hip/hip_bf16.h>

// y[b,i,j,u] = relu( sum_{c,h} w[u,c,i,h] * x[b,h,j,c] )
// B=16,H=64,W=64,C=64,U=128
// GEMM: M=(b,j)=1024, N=(i,u)=8192, K=(h,c)=4096, kappa=h*64+c.
//
// Pass 1a: Xb[b][h][j][c] = bf16(x)                      (8.39 MB, ws+0)
// Pass 1b: Wb[i][u][h][c] = bf16(w[u][c][i][h])          (64 MB,  ws+8388608)
// Pass 2 : gemm256 -- BM=BN=256, BK=32, 8 FAT waves (2x4, 128x64 each ->
//          fragment LDS traffic 22.9 B/KFLOP, MFMA-bound), 2 waves/SIMD,
//          SPLIT-K x2 (grid 256 = 128 tiles x 2 kslices of K=2048).
//          Triple-buffered LDS (96KB), counted vmcnt(4) (T4), m201-style
//          phases {ds_read || gload_lds -> bar -> lgkm0 -> setprio MFMA ->
//          bar} (T3/T5), XOR swizzle (T2), XCD swizzle (T1).
//          kslice0 -> raw f32 partial in d_out; kslice1 -> partial in ws.
// Pass 3 : add_relu: out = relu(P0 + P1).

typedef __attribute__((ext_vector_type(4))) float f32x4;
typedef __attribute__((ext_vector_type(8))) short bf16x8;
typedef __attribute__((ext_vector_type(4))) unsigned int u32x4;
typedef __attribute__((ext_vector_type(2))) unsigned int u32x2;
typedef unsigned short ushort_t;

static __device__ __forceinline__ unsigned int cvt_pk_bf16(float lo, float hi) {
  unsigned int r;
  asm("v_cvt_pk_bf16_f32 %0, %1, %2" : "=v"(r) : "v"(lo), "v"(hi));
  return r;
}

static __device__ __forceinline__ void async_copy16(void* lds, const void* g) {
  __builtin_amdgcn_global_load_lds(
      (const __attribute__((address_space(1))) unsigned int*)g,
      (__attribute__((address_space(3))) unsigned int*)lds, 16, 0, 0);
}

// ---------------- Pass 1a: x f32 -> bf16 (straight) ----------------
__global__ __launch_bounds__(256)
void conv_x(const float* __restrict__ X, ushort_t* __restrict__ Xb, int n4) {
  int idx = blockIdx.x * 256 + threadIdx.x;
  const int stride = gridDim.x * 256;
  for (; idx < n4; idx += stride) {
    f32x4 v = ((const f32x4*)X)[idx];
    u32x2 o;
    o.x = cvt_pk_bf16(v.x, v.y);
    o.y = cvt_pk_bf16(v.z, v.w);
    ((u32x2*)Xb)[idx] = o;
  }
}

// ---------------- Pass 1b: w[u][c][i][h] -> Wb[i][u][h][c] bf16 ----------------
__global__ __launch_bounds__(256)
void conv_w(const float* __restrict__ W, ushort_t* __restrict__ Wb) {
  __shared__ float T[64][65];  // [c][h], +1 pad
  const int bid = blockIdx.x;       // 8192 blocks = u*64 + i
  const int u = bid >> 6;
  const int i = bid & 63;
  const int t = threadIdx.x;

  const int hq = t & 15;            // 16B chunk of h-row
  const int c4 = t >> 4;            // 0..15
  const float* base = W + (((size_t)u * 64) * 64 + i) * 64;  // + c*4096 + h
#pragma unroll
  for (int it = 0; it < 4; ++it) {
    const int c = it * 16 + c4;
    f32x4 v = *(const f32x4*)(base + (size_t)c * 4096 + hq * 4);
    *(f32x4*)&T[c][hq * 4] = v;
  }
  __syncthreads();

  const int h = t >> 2;
  const int c0 = (t & 3) * 16;
  unsigned int pk[8];
#pragma unroll
  for (int q = 0; q < 8; ++q)
    pk[q] = cvt_pk_bf16(T[c0 + 2 * q][h], T[c0 + 2 * q + 1][h]);
  ushort_t* out = Wb + (((size_t)i * 128 + u) * 64 + h) * 64 + c0;
  ((u32x4*)out)[0] = *(u32x4*)&pk[0];
  ((u32x4*)out)[1] = *(u32x4*)&pk[4];
}

// ---------------- Pass 2: 256x256 fat-wave split-K GEMM ----------------
__global__ __launch_bounds__(512, 1)
void gemm256(const ushort_t* __restrict__ Xb, const ushort_t* __restrict__ Wb,
             float* __restrict__ P0, float* __restrict__ P1) {
  __shared__ ushort_t As[3][256 * 32];  // 16KB/buf, rows 64B, XOR-swizzled
  __shared__ ushort_t Bs[3][256 * 32];

  const int tid = threadIdx.x;
  const int lane = tid & 63;
  const int wid = tid >> 6;         // 8 waves
  const int wm = wid >> 2;          // 0..1 : 128-row m slab
  const int wn = wid & 3;           // 0..3 : 64-col n slab

  const int bid = blockIdx.x;       // 256 blocks; XCD-bijective swizzle
  const int wg = (bid & 7) * 32 + (bid >> 3);
  const int mt = wg & 3;            // 4 m-tiles of 256 (fastest: share B panel)
  const int rest = wg >> 2;
  const int ks = rest & 1;          // k-slice
  const int nt2 = rest >> 1;        // 32 n-tiles of 256 (an i-pair)

  const char* XbB = (const char*)Xb;
  const char* WbB = (const char*)Wb;
  const int kb6 = ks * 32;          // (ks*2048) >> 6

  // ---- staging: LDS dest lane-linear, source carries inverse XOR ----
  // per tile: A 16KB (2 x 16B/thread), B 16KB (2 x 16B/thread)
  int a_dst[2]; size_t a_srcb[2];
  int b_dst[2]; size_t b_srcb[2];
#pragma unroll
  for (int it = 0; it < 2; ++it) {
    const int flat = it * 8192 + tid * 16;
    const int row = flat >> 6;            // 0..255
    const int p = (flat >> 4) & 3;
    const int ps = p ^ ((row >> 1) & 3);
    a_dst[it] = flat;
    a_srcb[it] = (size_t)(mt * 4 + (row >> 6)) * 524288 +
                 (size_t)(row & 63) * 128 + ps * 16;
    b_dst[it] = flat;
    b_srcb[it] = (size_t)(nt2 * 256 + row) * 8192 + ps * 16;
  }

  // ---- fragment ds_read offsets ----
  int a_ro[2][4], b_ro[4];
#pragma unroll
  for (int mh = 0; mh < 2; ++mh)
#pragma unroll
    for (int f = 0; f < 4; ++f) {
      const int row = wm * 128 + mh * 64 + f * 16 + (lane & 15);
      a_ro[mh][f] = row * 64 + (((lane >> 4) ^ ((row >> 1) & 3)) << 4);
    }
#pragma unroll
  for (int f = 0; f < 4; ++f) {
    const int row = wn * 64 + f * 16 + (lane & 15);
    b_ro[f] = row * 64 + (((lane >> 4) ^ ((row >> 1) & 3)) << 4);
  }

  f32x4 acc[8][4];
#pragma unroll
  for (int i = 0; i < 8; ++i)
#pragma unroll
    for (int j = 0; j < 4; ++j) acc[i][j] = (f32x4){0.f, 0.f, 0.f, 0.f};

  auto stageA = [&](int buf, int T) {  // 2 loads
    char* la = (char*)&As[buf][0];
    const size_t koff = (size_t)(kb6 + (T >> 1)) * 8192 + (T & 1) * 64;
#pragma unroll
    for (int it = 0; it < 2; ++it)
      async_copy16(la + a_dst[it], XbB + a_srcb[it] + koff);
  };
  auto stageB = [&](int buf, int T) {  // 2 loads
    char* lb = (char*)&Bs[buf][0];
    const size_t koff = (size_t)(kb6 + (T >> 1)) * 128 + (T & 1) * 64;
#pragma unroll
    for (int it = 0; it < 2; ++it)
      async_copy16(lb + b_dst[it], WbB + b_srcb[it] + koff);
  };

  // ---- prologue: stage tiles 0,1 ; certify tile 0 (counted) ----
  stageA(0, 0); stageB(0, 0);
  stageA(1, 1); stageB(1, 1);
  asm volatile("s_waitcnt vmcnt(4)" ::: "memory");
  __builtin_amdgcn_s_barrier();

  int cur = 0, pre = 2;
  for (int t = 0; t < 64; ++t) {
    const char* ab = (const char*)&As[cur][0];
    const char* bb = (const char*)&Bs[cur][0];
    bf16x8 fa[4], fb[4], fa2[4];

    // ===== phase 0: read A(mh0)+B, issue stageA(t+2), MFMA mh0 =====
    __builtin_amdgcn_sched_barrier(0);
#pragma unroll
    for (int f = 0; f < 4; ++f) fa[f] = *(const bf16x8*)(ab + a_ro[0][f]);
#pragma unroll
    for (int f = 0; f < 4; ++f) fb[f] = *(const bf16x8*)(bb + b_ro[f]);
    if (t + 2 < 64) stageA(pre, t + 2);
    __builtin_amdgcn_s_barrier();
    asm volatile("s_waitcnt lgkmcnt(0)" ::: "memory");
    __builtin_amdgcn_sched_barrier(0);
    __builtin_amdgcn_s_setprio(1);
#pragma unroll
    for (int f = 0; f < 4; ++f)
#pragma unroll
      for (int nf = 0; nf < 4; ++nf)
        acc[f][nf] = __builtin_amdgcn_mfma_f32_16x16x32_bf16(
            fa[f], fb[nf], acc[f][nf], 0, 0, 0);
    __builtin_amdgcn_s_setprio(0);
    __builtin_amdgcn_s_barrier();

    // ===== phase 1: read A(mh1), issue stageB(t+2), MFMA mh1 =====
    __builtin_amdgcn_sched_barrier(0);
#pragma unroll
    for (int f = 0; f < 4; ++f) fa2[f] = *(const bf16x8*)(ab + a_ro[1][f]);
    if (t + 2 < 64) stageB(pre, t + 2);
    __builtin_amdgcn_s_barrier();
    asm volatile("s_waitcnt lgkmcnt(0)" ::: "memory");
    __builtin_amdgcn_sched_barrier(0);
    __builtin_amdgcn_s_setprio(1);
#pragma unroll
    for (int f = 0; f < 4; ++f)
#pragma unroll
      for (int nf = 0; nf < 4; ++nf)
        acc[4 + f][nf] = __builtin_amdgcn_mfma_f32_16x16x32_bf16(
            fa2[f], fb[nf], acc[4 + f][nf], 0, 0, 0);
    __builtin_amdgcn_s_setprio(0);
    // counted boundary: certify tile t+1; keep tile t+2's 4 loads in flight
    if (t < 62) {
      asm volatile("s_waitcnt vmcnt(4)" ::: "memory");
    } else if (t == 62) {
      asm volatile("s_waitcnt vmcnt(0)" ::: "memory");
    }
    __builtin_amdgcn_s_barrier();

    cur = (cur == 2) ? 0 : cur + 1;
    pre = (pre == 2) ? 0 : pre + 1;
  }

  // ---- epilogue: write raw f32 partial (relu deferred to add_relu) ----
  float* P = ks ? P1 : P0;
  const int rbase = (lane >> 4) * 4;
  const int cn = lane & 15;
#pragma unroll
  for (int mf = 0; mf < 8; ++mf) {
#pragma unroll
    for (int r = 0; r < 4; ++r) {
      const int m = mt * 256 + wm * 128 + mf * 16 + rbase + r;
      const int b = m >> 6;
      const int j = m & 63;
#pragma unroll
      for (int nf = 0; nf < 4; ++nf) {
        const int nloc = wn * 64 + nf * 16 + cn;
        const int i = nt2 * 2 + (nloc >> 7);
        const int u = nloc & 127;
        P[(((size_t)b * 64 + i) * 64 + j) * 128 + u] = acc[mf][nf][r];
      }
    }
  }
}

// ---------------- Pass 3: out = relu(P0 + P1) ----------------
__global__ __launch_bounds__(256)
void add_relu(float* __restrict__ Out, const float* __restrict__ P1, int n4) {
  int idx = blockIdx.x * 256 + threadIdx.x;
  const int stride = gridDim.x * 256;
  for (; idx < n4; idx += stride) {
    f32x4 a = ((const f32x4*)Out)[idx];
    f32x4 b = ((const f32x4*)P1)[idx];
    f32x4 r;
    r.x = fmaxf(a.x + b.x, 0.f);
    r.y = fmaxf(a.y + b.y, 0.f);
    r.z = fmaxf(a.z + b.z, 0.f);
    r.w = fmaxf(a.w + b.w, 0.f);
    ((f32x4*)Out)[idx] = r;
  }
}

// ---------------- Fallback A: round-6 gemm8 (proven 79us) ----------------
__global__ __launch_bounds__(512, 2)
void gemm8(const ushort_t* __restrict__ Xb, const ushort_t* __restrict__ Wb,
           float* __restrict__ O) {
  __shared__ ushort_t As[3][128 * 64];
  __shared__ ushort_t Bs[3][256 * 64];

  const int tid = threadIdx.x;
  const int lane = tid & 63;
  const int wid = tid >> 6;
  const int wm = wid >> 2;
  const int wn = wid & 3;

  const int bid = blockIdx.x;
  const int wg = (bid & 7) * 32 + (bid >> 3);
  const int mt = wg & 7;
  const int nt2 = wg >> 3;

  const char* XbB = (const char*)Xb;
  const char* WbB = (const char*)Wb;

  int a_dst[2]; size_t a_src[2];
#pragma unroll
  for (int it = 0; it < 2; ++it) {
    const int flat = it * 8192 + tid * 16;
    const int row = flat >> 7;
    const int p = (flat >> 4) & 7;
    const int b = mt * 2 + (row >> 6);
    const int j = row & 63;
    a_dst[it] = flat;
    a_src[it] = (size_t)b * 524288 + (size_t)j * 128 + ((p ^ (row & 7)) << 4);
  }
  int b_dst[4]; size_t b_src[4];
#pragma unroll
  for (int it = 0; it < 4; ++it) {
    const int flat = it * 8192 + tid * 16;
    const int nl = flat >> 7;
    const int p = (flat >> 4) & 7;
    b_dst[it] = flat;
    b_src[it] = (size_t)(nt2 * 256 + nl) * 8192 + ((p ^ (nl & 7)) << 4);
  }

  int a_ro[2][4], b_ro[2][4];
#pragma unroll
  for (int kk = 0; kk < 2; ++kk) {
#pragma unroll
    for (int f = 0; f < 4; ++f) {
      int row = wm * 64 + f * 16 + (lane & 15);
      int byte0 = row * 128 + kk * 64 + (lane >> 4) * 16;
      a_ro[kk][f] = byte0 ^ ((row & 7) << 4);
      row = wn * 64 + f * 16 + (lane & 15);
      byte0 = row * 128 + kk * 64 + (lane >> 4) * 16;
      b_ro[kk][f] = byte0 ^ ((row & 7) << 4);
    }
  }

  f32x4 acc[4][4];
#pragma unroll
  for (int i = 0; i < 4; ++i)
#pragma unroll
    for (int j = 0; j < 4; ++j) acc[i][j] = (f32x4){0.f, 0.f, 0.f, 0.f};

  auto stage = [&](int buf, int h) {
    char* la = (char*)&As[buf][0];
    char* lb = (char*)&Bs[buf][0];
#pragma unroll
    for (int it = 0; it < 2; ++it)
      async_copy16(la + a_dst[it], XbB + a_src[it] + (size_t)h * 8192);
#pragma unroll
    for (int it = 0; it < 4; ++it)
      async_copy16(lb + b_dst[it], WbB + b_src[it] + (size_t)h * 128);
  };
  auto stage3a = [&](int buf, int h) {
    char* la = (char*)&As[buf][0];
    char* lb = (char*)&Bs[buf][0];
#pragma unroll
    for (int it = 0; it < 2; ++it)
      async_copy16(la + a_dst[it], XbB + a_src[it] + (size_t)h * 8192);
    async_copy16(lb + b_dst[0], WbB + b_src[0] + (size_t)h * 128);
  };
  auto stage3b = [&](int buf, int h) {
    char* lb = (char*)&Bs[buf][0];
#pragma unroll
    for (int it = 1; it < 4; ++it)
      async_copy16(lb + b_dst[it], WbB + b_src[it] + (size_t)h * 128);
  };

  bf16x8 fa0[4], fb0[4], fa1[4], fb1[4];
  auto readFrags = [&](bf16x8 (&fa)[4], bf16x8 (&fb)[4], int buf, int kk) {
    const char* ab = (const char*)&As[buf][0];
    const char* bb = (const char*)&Bs[buf][0];
#pragma unroll
    for (int f = 0; f < 4; ++f) fa[f] = *(const bf16x8*)(ab + a_ro[kk][f]);
#pragma unroll
    for (int f = 0; f < 4; ++f) fb[f] = *(const bf16x8*)(bb + b_ro[kk][f]);
  };

  stage(0, 0);
  stage(1, 1);
  asm volatile("s_waitcnt vmcnt(6)" ::: "memory");
  __builtin_amdgcn_s_barrier();
  readFrags(fa0, fb0, 0, 0);

  int cur = 0, nxt = 1, pre = 2;
  for (int t = 0; t < 64; ++t) {
    __builtin_amdgcn_sched_barrier(0);
    readFrags(fa1, fb1, cur, 1);
    if (t + 2 < 64) stage3a(pre, t + 2);
    if (t < 62) {
      asm volatile("s_waitcnt vmcnt(3)" ::: "memory");
    } else {
      asm volatile("s_waitcnt vmcnt(0)" ::: "memory");
    }
    __builtin_amdgcn_sched_barrier(0);
    __builtin_amdgcn_s_barrier();
    __builtin_amdgcn_s_setprio(1);
#pragma unroll
    for (int mf = 0; mf < 4; ++mf)
#pragma unroll
      for (int nf = 0; nf < 4; ++nf)
        acc[mf][nf] = __builtin_amdgcn_mfma_f32_16x16x32_bf16(
            fa0[mf], fb0[nf], acc[mf][nf], 0, 0, 0);
    __builtin_amdgcn_s_setprio(0);
    __builtin_amdgcn_s_barrier();

    __builtin_amdgcn_sched_barrier(0);
    if (t + 1 < 64) readFrags(fa0, fb0, nxt, 0);
    if (t + 2 < 64) stage3b(pre, t + 2);
    __builtin_amdgcn_sched_barrier(0);
    __builtin_amdgcn_s_barrier();
    __builtin_amdgcn_s_setprio(1);
#pragma unroll
    for (int mf = 0; mf < 4; ++mf)
#pragma unroll
      for (int nf = 0; nf < 4; ++nf)
        acc[mf][nf] = __builtin_amdgcn_mfma_f32_16x16x32_bf16(
            fa1[mf], fb1[nf], acc[mf][nf], 0, 0, 0);
    __builtin_amdgcn_s_setprio(0);
    __builtin_amdgcn_s_barrier();

    cur = (cur == 2) ? 0 : cur + 1;
    nxt = (nxt == 2) ? 0 : nxt + 1;
    pre = (pre == 2) ? 0 : pre + 1;
  }

  const int rbase = (lane >> 4) * 4;
  const int cn = lane & 15;
#pragma unroll
  for (int mf = 0; mf < 4; ++mf) {
#pragma unroll
    for (int r = 0; r < 4; ++r) {
      const int ml = wm * 64 + mf * 16 + rbase + r;
      const int m = mt * 128 + ml;
      const int b = m >> 6;
      const int j = m & 63;
#pragma unroll
      for (int nf = 0; nf < 4; ++nf) {
        const int nloc = wn * 64 + nf * 16 + cn;
        const int i = nt2 * 2 + (nloc >> 7);
        const int u = nloc & 127;
        O[(((size_t)b * 64 + i) * 64 + j) * 128 + u] = fmaxf(acc[mf][nf][r], 0.f);
      }
    }
  }
}

// ---------------- Fallback B: round-1 fused kernel (tiny ws) ----------------
__global__ __launch_bounds__(256, 2)
void fused_gemm(const float* __restrict__ X, const float* __restrict__ Wt,
                float* __restrict__ O) {
  __shared__ ushort_t As[2][128 * 64];
  __shared__ ushort_t Bs[2][128 * 64];
  const int tid = threadIdx.x;
  const int lane = tid & 63;
  const int wid = tid >> 6;
  const int wm = wid >> 1;
  const int wn = wid & 1;
  const int bid = blockIdx.x;
  const int wg = (bid & 7) * 64 + (bid >> 3);
  const int mt = wg & 7;
  const int nt = wg >> 3;
  const int a_ml = tid >> 1;
  const int a_hp = (tid & 1) * 2;
  const int a_b = (mt * 128 + a_ml) >> 6;
  const int a_j = a_ml & 63;
  const float* a_base = X + ((size_t)a_b << 18) + ((size_t)a_j << 6);
  const int b_nl = tid >> 1;
  const int b_c8 = (tid & 1) * 8;
  const float* b_base = Wt + ((size_t)b_nl << 18) + ((size_t)nt << 6);
  f32x4 ra[2][4];
  f32x4 rb[8];
  f32x4 acc[4][4];
#pragma unroll
  for (int i = 0; i < 4; ++i)
#pragma unroll
    for (int j = 0; j < 4; ++j) acc[i][j] = (f32x4){0.f, 0.f, 0.f, 0.f};
  auto stage_load = [&](int t) {
    const int th = t & 15;
    const int tc = t >> 4;
    const int c0 = tc * 16;
    const int h0 = th * 4;
#pragma unroll
    for (int s = 0; s < 2; ++s) {
      const float* p = a_base + (size_t)(h0 + a_hp + s) * 4096 + c0;
#pragma unroll
      for (int q = 0; q < 4; ++q) ra[s][q] = ((const f32x4*)p)[q];
    }
#pragma unroll
    for (int q = 0; q < 8; ++q)
      rb[q] = *(const f32x4*)(b_base + (size_t)(c0 + b_c8 + q) * 4096 + h0);
  };
  auto stage_write = [&](int buf) {
    char* abase = (char*)&As[buf][0];
    const int swa = (a_ml & 7) << 4;
#pragma unroll
    for (int s = 0; s < 2; ++s) {
      u32x4 lo, hi;
      lo.x = cvt_pk_bf16(ra[s][0].x, ra[s][0].y);
      lo.y = cvt_pk_bf16(ra[s][0].z, ra[s][0].w);
      lo.z = cvt_pk_bf16(ra[s][1].x, ra[s][1].y);
      lo.w = cvt_pk_bf16(ra[s][1].z, ra[s][1].w);
      hi.x = cvt_pk_bf16(ra[s][2].x, ra[s][2].y);
      hi.y = cvt_pk_bf16(ra[s][2].z, ra[s][2].w);
      hi.z = cvt_pk_bf16(ra[s][3].x, ra[s][3].y);
      hi.w = cvt_pk_bf16(ra[s][3].z, ra[s][3].w);
      const int byte0 = a_ml * 128 + (a_hp + s) * 32;
      *(u32x4*)(abase + (byte0 ^ swa)) = lo;
      *(u32x4*)(abase + ((byte0 + 16) ^ swa)) = hi;
    }
    char* bbase = (char*)&Bs[buf][0];
    const int swb = (b_nl & 7) << 4;
#pragma unroll
    for (int hl = 0; hl < 4; ++hl) {
      u32x4 v;
      v.x = cvt_pk_bf16(rb[0][hl], rb[1][hl]);
      v.y = cvt_pk_bf16(rb[2][hl], rb[3][hl]);
      v.z = cvt_pk_bf16(rb[4][hl], rb[5][hl]);
      v.w = cvt_pk_bf16(rb[6][hl], rb[7][hl]);
      const int byte0 = b_nl * 128 + (hl * 16 + b_c8) * 2;
      *(u32x4*)(bbase + (byte0 ^ swb)) = v;
    }
  };
  auto compute = [&](int buf) {
    const char* abase = (const char*)&As[buf][0];
    const char* bbase = (const char*)&Bs[buf][0];
#pragma unroll
    for (int kk = 0; kk < 2; ++kk) {
      bf16x8 af[4], bfr[4];
#pragma unroll
      for (int mf = 0; mf < 4; ++mf) {
        const int row = wm * 64 + mf * 16 + (lane & 15);
        const int byte0 = row * 128 + kk * 64 + (lane >> 4) * 16;
        af[mf] = *(const bf16x8*)(abase + (byte0 ^ ((row & 7) << 4)));
      }
#pragma unroll
      for (int nf = 0; nf < 4; ++nf) {
        const int row = wn * 64 + nf * 16 + (lane & 15);
        const int byte0 = row * 128 + kk * 64 + (lane >> 4) * 16;
        bfr[nf] = *(const bf16x8*)(bbase + (byte0 ^ ((row & 7) << 4)));
      }
#pragma unroll
      for (int mf = 0; mf < 4; ++mf)
#pragma unroll
        for (int nf = 0; nf < 4; ++nf)
          acc[mf][nf] = __builtin_amdgcn_mfma_f32_16x16x32_bf16(
              af[mf], bfr[nf], acc[mf][nf], 0, 0, 0);
    }
  };
  stage_load(0);
  stage_write(0);
  __syncthreads();
  int cur = 0;
  for (int t = 0; t < 64; ++t) {
    if (t + 1 < 64) stage_load(t + 1);
    compute(cur);
    if (t + 1 < 64) stage_write(cur ^ 1);
    __syncthreads();
    cur ^= 1;
  }
  const int rbase = (lane >> 4) * 4;
  const int cn = lane & 15;
#pragma unroll
  for (int mf = 0; mf < 4; ++mf) {
#pragma unroll
    for (int r = 0; r < 4; ++r) {
      const int ml = wm * 64 + mf * 16 + rbase + r;
      const int m = mt * 128 + ml;
      const int b = m >> 6;
      const int j = m & 63;
      float* orow = O + (((size_t)b * 64 + nt) * 64 + j) * 128;
#pragma unroll
      for (int nf = 0; nf < 4; ++nf) {
        const int u = wn * 64 + nf * 16 + cn;
        orow[u] = fmaxf(acc[mf][nf][r], 0.f);
      }
    }
  }
}

extern "C" void kernel_launch(void* const* d_in, const int* in_sizes, int n_in,
                              void* d_out, int out_size, void* d_ws, size_t ws_size,
                              hipStream_t stream) {
  const float* x = (const float*)d_in[0];   // (16,64,64,64) f32
  const float* w = (const float*)d_in[1];   // (128,64,64,64) f32
  float* out = (float*)d_out;               // (16,64,64,128) f32

  const size_t XB_BYTES = (size_t)16 * 64 * 64 * 64 * 2;    // 8,388,608
  const size_t WB_BYTES = (size_t)64 * 128 * 64 * 64 * 2;   // 67,108,864
  const size_t P1_BYTES = (size_t)16 * 64 * 64 * 128 * 4;   // 33,554,432

  if (ws_size >= XB_BYTES + WB_BYTES + P1_BYTES) {
    ushort_t* Xb = (ushort_t*)d_ws;
    ushort_t* Wb = (ushort_t*)((char*)d_ws + XB_BYTES);
    float* P1 = (float*)((char*)d_ws + XB_BYTES + WB_BYTES);
    hipLaunchKernelGGL(conv_x, dim3(1024), dim3(256), 0, stream, x, Xb,
                       (int)(16 * 64 * 64 * 64 / 4));
    hipLaunchKernelGGL(conv_w, dim3(8192), dim3(256), 0, stream, w, Wb);
    hipLaunchKernelGGL(gemm256, dim3(256), dim3(512), 0, stream, Xb, Wb, out, P1);
    hipLaunchKernelGGL(add_relu, dim3(2048), dim3(256), 0, stream, out, P1,
                       (int)(16 * 64 * 64 * 128 / 4));
  } else if (ws_size >= XB_BYTES + WB_BYTES) {
    ushort_t* Xb = (ushort_t*)d_ws;
    ushort_t* Wb = (ushort_t*)((char*)d_ws + XB_BYTES);
    hipLaunchKernelGGL(conv_x, dim3(1024), dim3(256), 0, stream, x, Xb,
                       (int)(16 * 64 * 64 * 64 / 4));
    hipLaunchKernelGGL(conv_w, dim3(8192), dim3(256), 0, stream, w, Wb);
    hipLaunchKernelGGL(gemm8, dim3(256), dim3(512), 0, stream, Xb, Wb, out);
  } else {
    hipLaunchKernelGGL(fused_gemm, dim3(512), dim3(256), 0, stream, x, w, out);
  }
}

// Round 10
// 127.389 us; speedup vs baseline: 1.1620x; 1.0359x over previous
//
#include <hip/hip_runtime.h>
#include <hip/hip_bf16.h>

// y[b,i,j,u] = relu( sum_{c,h} w[u,c,i,h] * x[b,h,j,c] )
// B=16,H=64,W=64,C=64,U=128
// GEMM: M=(b,j)=1024, N=(i,u)=8192, K=(h,c)=4096, kappa=h*64+c.
//
// Pass 1a: Xb[b][h][j][c] = bf16(x)                      (8.39 MB, ws+0)
// Pass 1b: Wb[i][u][h][c] = bf16(w[u][c][i][h])          (64 MB,  ws+8388608)
// Pass 2 : gemm2b -- BM=BN=128, BK=32, 4 waves (2x2, 64x64 each), LDS 48KB
//          (3 x 8KB per operand) -> TWO blocks/CU (8 waves/CU, 2/SIMD) so
//          one block's MFMA fills the other's sync stalls (m114 overlap).
//          Round-6 proven machinery: triple buffer, read-ahead fragments
//          (frags of t+1 ds_read during t's MFMA), counted vmcnt(4) (T4),
//          setprio (T5), 2-slot XOR swizzle (T2), XCD-bijective grid (T1).
//          128 K-steps of 32 kappa; K-tile T = h=(T>>1), c-half=(T&1)*32.

typedef __attribute__((ext_vector_type(4))) float f32x4;
typedef __attribute__((ext_vector_type(8))) short bf16x8;
typedef __attribute__((ext_vector_type(4))) unsigned int u32x4;
typedef __attribute__((ext_vector_type(2))) unsigned int u32x2;
typedef unsigned short ushort_t;

static __device__ __forceinline__ unsigned int cvt_pk_bf16(float lo, float hi) {
  unsigned int r;
  asm("v_cvt_pk_bf16_f32 %0, %1, %2" : "=v"(r) : "v"(lo), "v"(hi));
  return r;
}

static __device__ __forceinline__ void async_copy16(void* lds, const void* g) {
  __builtin_amdgcn_global_load_lds(
      (const __attribute__((address_space(1))) unsigned int*)g,
      (__attribute__((address_space(3))) unsigned int*)lds, 16, 0, 0);
}

// ---------------- Pass 1a: x f32 -> bf16 (straight) ----------------
__global__ __launch_bounds__(256)
void conv_x(const float* __restrict__ X, ushort_t* __restrict__ Xb, int n4) {
  int idx = blockIdx.x * 256 + threadIdx.x;
  const int stride = gridDim.x * 256;
  for (; idx < n4; idx += stride) {
    f32x4 v = ((const f32x4*)X)[idx];
    u32x2 o;
    o.x = cvt_pk_bf16(v.x, v.y);
    o.y = cvt_pk_bf16(v.z, v.w);
    ((u32x2*)Xb)[idx] = o;
  }
}

// ---------------- Pass 1b: w[u][c][i][h] -> Wb[i][u][h][c] bf16 ----------------
__global__ __launch_bounds__(256)
void conv_w(const float* __restrict__ W, ushort_t* __restrict__ Wb) {
  __shared__ float T[64][65];  // [c][h], +1 pad
  const int bid = blockIdx.x;       // 8192 blocks = u*64 + i
  const int u = bid >> 6;
  const int i = bid & 63;
  const int t = threadIdx.x;

  const int hq = t & 15;            // 16B chunk of h-row
  const int c4 = t >> 4;            // 0..15
  const float* base = W + (((size_t)u * 64) * 64 + i) * 64;  // + c*4096 + h
#pragma unroll
  for (int it = 0; it < 4; ++it) {
    const int c = it * 16 + c4;
    f32x4 v = *(const f32x4*)(base + (size_t)c * 4096 + hq * 4);
    *(f32x4*)&T[c][hq * 4] = v;
  }
  __syncthreads();

  const int h = t >> 2;
  const int c0 = (t & 3) * 16;
  unsigned int pk[8];
#pragma unroll
  for (int q = 0; q < 8; ++q)
    pk[q] = cvt_pk_bf16(T[c0 + 2 * q][h], T[c0 + 2 * q + 1][h]);
  ushort_t* out = Wb + (((size_t)i * 128 + u) * 64 + h) * 64 + c0;
  ((u32x4*)out)[0] = *(u32x4*)&pk[0];
  ((u32x4*)out)[1] = *(u32x4*)&pk[4];
}

// ---------------- Pass 2: BK=32 triple-buffer, 2 blocks/CU ----------------
__global__ __launch_bounds__(256, 2)
void gemm2b(const ushort_t* __restrict__ Xb, const ushort_t* __restrict__ Wb,
            float* __restrict__ O) {
  __shared__ ushort_t As[3][128 * 32];  // 8KB each, 64B rows, XOR-swizzled
  __shared__ ushort_t Bs[3][128 * 32];  // total 48KB -> 2 blocks/CU

  const int tid = threadIdx.x;
  const int lane = tid & 63;
  const int wid = tid >> 6;         // 4 waves
  const int wm = wid >> 1;          // 0..1 : 64-row m slab
  const int wn = wid & 1;           // 0..1 : 64-col n slab

  const int bid = blockIdx.x;       // 512 blocks; XCD-bijective (512%8==0)
  const int wg = (bid & 7) * 64 + (bid >> 3);
  const int mt = wg & 7;            // 8 m-tiles of 128
  const int nt = wg >> 3;           // 64 n-tiles of 128 == output i

  const char* XbB = (const char*)Xb;
  const char* WbB = (const char*)Wb;

  // ---- staging geometry: LDS dest lane-linear; source carries inverse XOR ----
  // per K-tile: A 128 rows x 64B = 8KB (2 x 16B/thread), B same.
  int dst_off[2]; size_t a_srcb[2], b_srcb[2];
#pragma unroll
  for (int it = 0; it < 2; ++it) {
    const int flat = it * 4096 + tid * 16;
    const int row = flat >> 6;            // 0..127
    const int p = (flat >> 4) & 3;        // 16B slot in 64B row
    const int ps = p ^ (row & 3);
    dst_off[it] = flat;
    a_srcb[it] = (size_t)(mt * 2 + (row >> 6)) * 524288 +
                 (size_t)(row & 63) * 128 + ps * 16;
    b_srcb[it] = (size_t)(nt * 128 + row) * 8192 + ps * 16;
  }

  // ---- fragment ds_read offsets (one 32-kappa slice per step) ----
  int a_ro[4], b_ro[4];
#pragma unroll
  for (int f = 0; f < 4; ++f) {
    int row = wm * 64 + f * 16 + (lane & 15);
    a_ro[f] = row * 64 + (((lane >> 4) ^ (row & 3)) << 4);
    row = wn * 64 + f * 16 + (lane & 15);
    b_ro[f] = row * 64 + (((lane >> 4) ^ (row & 3)) << 4);
  }

  f32x4 acc[4][4];
#pragma unroll
  for (int i = 0; i < 4; ++i)
#pragma unroll
    for (int j = 0; j < 4; ++j) acc[i][j] = (f32x4){0.f, 0.f, 0.f, 0.f};

  auto stage = [&](int buf, int T) {   // 4 async loads (2 A + 2 B)
    char* la = (char*)&As[buf][0];
    char* lb = (char*)&Bs[buf][0];
    const size_t ka = (size_t)(T >> 1) * 8192 + (size_t)(T & 1) * 64;
    const size_t kb = (size_t)(T >> 1) * 128 + (size_t)(T & 1) * 64;
#pragma unroll
    for (int it = 0; it < 2; ++it)
      async_copy16(la + dst_off[it], XbB + a_srcb[it] + ka);
#pragma unroll
    for (int it = 0; it < 2; ++it)
      async_copy16(lb + dst_off[it], WbB + b_srcb[it] + kb);
  };

  bf16x8 faA[4], fbA[4], faB[4], fbB[4];
  auto readFragsTo = [&](bf16x8 (&fa)[4], bf16x8 (&fb)[4], int buf) {
    const char* ab = (const char*)&As[buf][0];
    const char* bb = (const char*)&Bs[buf][0];
#pragma unroll
    for (int f = 0; f < 4; ++f) fa[f] = *(const bf16x8*)(ab + a_ro[f]);
#pragma unroll
    for (int f = 0; f < 4; ++f) fb[f] = *(const bf16x8*)(bb + b_ro[f]);
  };

  int cur = 0, nxt = 1, pre = 2;

  // one K-step; fragments of t were preloaded, preload t+1 under the MFMAs
  auto step = [&](int t, bf16x8 (&fac)[4], bf16x8 (&fbc)[4],
                  bf16x8 (&fan)[4], bf16x8 (&fbn)[4]) {
    if (t + 2 < 128) stage(pre, t + 2);
    if (t < 126) {
      asm volatile("s_waitcnt vmcnt(4)" ::: "memory");  // certify t+1
    } else {
      asm volatile("s_waitcnt vmcnt(0)" ::: "memory");
    }
    __builtin_amdgcn_sched_barrier(0);
    __builtin_amdgcn_s_barrier();
    if (t + 1 < 128) readFragsTo(fan, fbn, nxt);
    __builtin_amdgcn_s_setprio(1);
#pragma unroll
    for (int mf = 0; mf < 4; ++mf)
#pragma unroll
      for (int nf = 0; nf < 4; ++nf)
        acc[mf][nf] = __builtin_amdgcn_mfma_f32_16x16x32_bf16(
            fac[mf], fbc[nf], acc[mf][nf], 0, 0, 0);
    __builtin_amdgcn_s_setprio(0);
    __builtin_amdgcn_s_barrier();
    cur = (cur == 2) ? 0 : cur + 1;
    nxt = (nxt == 2) ? 0 : nxt + 1;
    pre = (pre == 2) ? 0 : pre + 1;
  };

  // ---- prologue: stage K-tiles 0,1 ; certify 0 ; preload its fragments ----
  stage(0, 0);
  stage(1, 1);
  asm volatile("s_waitcnt vmcnt(4)" ::: "memory");
  __builtin_amdgcn_s_barrier();
  readFragsTo(faA, fbA, 0);

  // ---- main loop: 128 K-steps, 2x unrolled for static fragment sets ----
  for (int t = 0; t < 128; t += 2) {
    step(t, faA, fbA, faB, fbB);
    step(t + 1, faB, fbB, faA, fbA);
  }

  // ---- epilogue: relu + scatter to y[b, i=nt, j, u] ----
  const int rbase = (lane >> 4) * 4;
  const int cn = lane & 15;
#pragma unroll
  for (int mf = 0; mf < 4; ++mf) {
#pragma unroll
    for (int r = 0; r < 4; ++r) {
      const int ml = wm * 64 + mf * 16 + rbase + r;
      const int m = mt * 128 + ml;
      const int b = m >> 6;
      const int j = m & 63;
      float* orow = O + (((size_t)b * 64 + nt) * 64 + j) * 128;
#pragma unroll
      for (int nf = 0; nf < 4; ++nf) {
        const int u = wn * 64 + nf * 16 + cn;
        orow[u] = fmaxf(acc[mf][nf][r], 0.f);
      }
    }
  }
}

// ---------------- Fallback: round-1 fused kernel (tiny ws) ----------------
__global__ __launch_bounds__(256, 2)
void fused_gemm(const float* __restrict__ X, const float* __restrict__ Wt,
                float* __restrict__ O) {
  __shared__ ushort_t As[2][128 * 64];
  __shared__ ushort_t Bs[2][128 * 64];
  const int tid = threadIdx.x;
  const int lane = tid & 63;
  const int wid = tid >> 6;
  const int wm = wid >> 1;
  const int wn = wid & 1;
  const int bid = blockIdx.x;
  const int wg = (bid & 7) * 64 + (bid >> 3);
  const int mt = wg & 7;
  const int nt = wg >> 3;
  const int a_ml = tid >> 1;
  const int a_hp = (tid & 1) * 2;
  const int a_b = (mt * 128 + a_ml) >> 6;
  const int a_j = a_ml & 63;
  const float* a_base = X + ((size_t)a_b << 18) + ((size_t)a_j << 6);
  const int b_nl = tid >> 1;
  const int b_c8 = (tid & 1) * 8;
  const float* b_base = Wt + ((size_t)b_nl << 18) + ((size_t)nt << 6);
  f32x4 ra[2][4];
  f32x4 rb[8];
  f32x4 acc[4][4];
#pragma unroll
  for (int i = 0; i < 4; ++i)
#pragma unroll
    for (int j = 0; j < 4; ++j) acc[i][j] = (f32x4){0.f, 0.f, 0.f, 0.f};
  auto stage_load = [&](int t) {
    const int th = t & 15;
    const int tc = t >> 4;
    const int c0 = tc * 16;
    const int h0 = th * 4;
#pragma unroll
    for (int s = 0; s < 2; ++s) {
      const float* p = a_base + (size_t)(h0 + a_hp + s) * 4096 + c0;
#pragma unroll
      for (int q = 0; q < 4; ++q) ra[s][q] = ((const f32x4*)p)[q];
    }
#pragma unroll
    for (int q = 0; q < 8; ++q)
      rb[q] = *(const f32x4*)(b_base + (size_t)(c0 + b_c8 + q) * 4096 + h0);
  };
  auto stage_write = [&](int buf) {
    char* abase = (char*)&As[buf][0];
    const int swa = (a_ml & 7) << 4;
#pragma unroll
    for (int s = 0; s < 2; ++s) {
      u32x4 lo, hi;
      lo.x = cvt_pk_bf16(ra[s][0].x, ra[s][0].y);
      lo.y = cvt_pk_bf16(ra[s][0].z, ra[s][0].w);
      lo.z = cvt_pk_bf16(ra[s][1].x, ra[s][1].y);
      lo.w = cvt_pk_bf16(ra[s][1].z, ra[s][1].w);
      hi.x = cvt_pk_bf16(ra[s][2].x, ra[s][2].y);
      hi.y = cvt_pk_bf16(ra[s][2].z, ra[s][2].w);
      hi.z = cvt_pk_bf16(ra[s][3].x, ra[s][3].y);
      hi.w = cvt_pk_bf16(ra[s][3].z, ra[s][3].w);
      const int byte0 = a_ml * 128 + (a_hp + s) * 32;
      *(u32x4*)(abase + (byte0 ^ swa)) = lo;
      *(u32x4*)(abase + ((byte0 + 16) ^ swa)) = hi;
    }
    char* bbase = (char*)&Bs[buf][0];
    const int swb = (b_nl & 7) << 4;
#pragma unroll
    for (int hl = 0; hl < 4; ++hl) {
      u32x4 v;
      v.x = cvt_pk_bf16(rb[0][hl], rb[1][hl]);
      v.y = cvt_pk_bf16(rb[2][hl], rb[3][hl]);
      v.z = cvt_pk_bf16(rb[4][hl], rb[5][hl]);
      v.w = cvt_pk_bf16(rb[6][hl], rb[7][hl]);
      const int byte0 = b_nl * 128 + (hl * 16 + b_c8) * 2;
      *(u32x4*)(bbase + (byte0 ^ swb)) = v;
    }
  };
  auto compute = [&](int buf) {
    const char* abase = (const char*)&As[buf][0];
    const char* bbase = (const char*)&Bs[buf][0];
#pragma unroll
    for (int kk = 0; kk < 2; ++kk) {
      bf16x8 af[4], bfr[4];
#pragma unroll
      for (int mf = 0; mf < 4; ++mf) {
        const int row = wm * 64 + mf * 16 + (lane & 15);
        const int byte0 = row * 128 + kk * 64 + (lane >> 4) * 16;
        af[mf] = *(const bf16x8*)(abase + (byte0 ^ ((row & 7) << 4)));
      }
#pragma unroll
      for (int nf = 0; nf < 4; ++nf) {
        const int row = wn * 64 + nf * 16 + (lane & 15);
        const int byte0 = row * 128 + kk * 64 + (lane >> 4) * 16;
        bfr[nf] = *(const bf16x8*)(bbase + (byte0 ^ ((row & 7) << 4)));
      }
#pragma unroll
      for (int mf = 0; mf < 4; ++mf)
#pragma unroll
        for (int nf = 0; nf < 4; ++nf)
          acc[mf][nf] = __builtin_amdgcn_mfma_f32_16x16x32_bf16(
              af[mf], bfr[nf], acc[mf][nf], 0, 0, 0);
    }
  };
  stage_load(0);
  stage_write(0);
  __syncthreads();
  int cur = 0;
  for (int t = 0; t < 64; ++t) {
    if (t + 1 < 64) stage_load(t + 1);
    compute(cur);
    if (t + 1 < 64) stage_write(cur ^ 1);
    __syncthreads();
    cur ^= 1;
  }
  const int rbase = (lane >> 4) * 4;
  const int cn = lane & 15;
#pragma unroll
  for (int mf = 0; mf < 4; ++mf) {
#pragma unroll
    for (int r = 0; r < 4; ++r) {
      const int ml = wm * 64 + mf * 16 + rbase + r;
      const int m = mt * 128 + ml;
      const int b = m >> 6;
      const int j = m & 63;
      float* orow = O + (((size_t)b * 64 + nt) * 64 + j) * 128;
#pragma unroll
      for (int nf = 0; nf < 4; ++nf) {
        const int u = wn * 64 + nf * 16 + cn;
        orow[u] = fmaxf(acc[mf][nf][r], 0.f);
      }
    }
  }
}

extern "C" void kernel_launch(void* const* d_in, const int* in_sizes, int n_in,
                              void* d_out, int out_size, void* d_ws, size_t ws_size,
                              hipStream_t stream) {
  const float* x = (const float*)d_in[0];   // (16,64,64,64) f32
  const float* w = (const float*)d_in[1];   // (128,64,64,64) f32
  float* out = (float*)d_out;               // (16,64,64,128) f32

  const size_t XB_BYTES = (size_t)16 * 64 * 64 * 64 * 2;    // 8,388,608
  const size_t WB_BYTES = (size_t)64 * 128 * 64 * 64 * 2;   // 67,108,864

  if (ws_size >= XB_BYTES + WB_BYTES) {
    ushort_t* Xb = (ushort_t*)d_ws;
    ushort_t* Wb = (ushort_t*)((char*)d_ws + XB_BYTES);
    hipLaunchKernelGGL(conv_x, dim3(1024), dim3(256), 0, stream, x, Xb,
                       (int)(16 * 64 * 64 * 64 / 4));
    hipLaunchKernelGGL(conv_w, dim3(8192), dim3(256), 0, stream, w, Wb);
    hipLaunchKernelGGL(gemm2b, dim3(512), dim3(256), 0, stream, Xb, Wb, out);
  } else {
    hipLaunchKernelGGL(fused_gemm, dim3(512), dim3(256), 0, stream, x, w, out);
  }
}